// Round 1
// baseline (518.335 us; speedup 1.0000x reference)
//
#include <hip/hip_runtime.h>
#include <math.h>

#define SEQL 4096

__device__ __forceinline__ float sigmoid_f(float x){ return 1.0f/(1.0f+expf(-x)); }

// ---------------- conv 3x3, pad 1, 64x64 image ----------------
template<int CI, bool RELU, bool RES>
__global__ __launch_bounds__(256) void conv3x3_k(const float* __restrict__ in,
    const float* __restrict__ wgt, const float* __restrict__ bias,
    const float* __restrict__ res, float* __restrict__ out)
{
  const int lane = threadIdx.x;                 // w, 0..63 (full wave = one row)
  const int h0   = blockIdx.x*16 + threadIdx.y*4;
  const int co   = blockIdx.y;
  const int b    = blockIdx.z;
  const int CO   = gridDim.y;
  float bv = bias[co];
  float acc[4] = {bv,bv,bv,bv};
  const float* wp = wgt + (size_t)co*CI*9;
  for (int ci=0; ci<CI; ++ci){
    const float* p = in + ((size_t)(b*CI+ci))*4096;
    float w_[9];
    #pragma unroll
    for (int k=0;k<9;++k) w_[k] = wp[ci*9+k];
    #pragma unroll
    for (int j=0;j<6;++j){
      int hh = h0 - 1 + j;                      // wave-uniform branch
      float mid = (hh>=0 && hh<64) ? p[hh*64+lane] : 0.0f;
      float lv = __shfl_up(mid,1);   if (lane==0)  lv = 0.0f;
      float rv = __shfl_down(mid,1); if (lane==63) rv = 0.0f;
      #pragma unroll
      for (int k=0;k<4;++k){
        int kh = j - k;                          // output row k uses input rows k..k+2
        if (kh>=0 && kh<3)
          acc[k] += lv*w_[kh*3+0] + mid*w_[kh*3+1] + rv*w_[kh*3+2];
      }
    }
  }
  size_t ob = ((size_t)(b*CO+co))*4096 + (size_t)h0*64 + lane;
  #pragma unroll
  for (int k=0;k<4;++k){
    float v = acc[k];
    if constexpr (RES)  v += res[ob + k*64];
    if constexpr (RELU) v = fmaxf(v, 0.0f);
    out[ob + k*64] = v;
  }
}

// ---------------- LayerNorm(32) + in_proj (32->128) + silu on z half --------
// x2 flat rows of 32 are contiguous (pure reshape). Outputs (b,d,l) layout.
__global__ __launch_bounds__(256) void ln_inproj_k(const float* __restrict__ x2,
    const float* __restrict__ g, const float* __restrict__ be,
    const float* __restrict__ Wip, float* __restrict__ xm_pre, float* __restrict__ sz)
{
  __shared__ float xn[64][33];
  const int tid = threadIdx.x, lane = tid & 63, ty = tid >> 6;
  const int bi = blockIdx.x >> 6;
  const int l0 = (blockIdx.x & 63) << 6;
  if (ty == 0){
    const float* row = x2 + (size_t)bi*131072 + (size_t)(l0+lane)*32;
    float v[32];
    #pragma unroll
    for (int c=0;c<32;c+=4){
      float4 f = *(const float4*)(row + c);
      v[c]=f.x; v[c+1]=f.y; v[c+2]=f.z; v[c+3]=f.w;
    }
    // numpy pairwise (8-way) mean
    float p[8];
    #pragma unroll
    for (int j2=0;j2<8;++j2) p[j2]=v[j2];
    #pragma unroll
    for (int i=8;i<32;i+=8){
      #pragma unroll
      for (int j2=0;j2<8;++j2) p[j2]+=v[i+j2];
    }
    float mu = (((p[0]+p[1])+(p[2]+p[3]))+((p[4]+p[5])+(p[6]+p[7]))) * 0.03125f;
    float q[8];
    #pragma unroll
    for (int j2=0;j2<8;++j2){ float dd=v[j2]-mu; q[j2]=dd*dd; }
    #pragma unroll
    for (int i=8;i<32;i+=8){
      #pragma unroll
      for (int j2=0;j2<8;++j2){ float dd=v[i+j2]-mu; q[j2]+=dd*dd; }
    }
    float var = (((q[0]+q[1])+(q[2]+q[3]))+((q[4]+q[5])+(q[6]+q[7]))) * 0.03125f;
    float rstd = 1.0f / sqrtf(var + 1e-5f);
    #pragma unroll
    for (int c=0;c<32;++c) xn[lane][c] = (v[c]-mu)*rstd*g[c] + be[c];
  }
  __syncthreads();
  float xv[32];
  #pragma unroll
  for (int c=0;c<32;++c) xv[c] = xn[lane][c];
  const int j0 = ty*32;
  for (int jj=0;jj<32;++jj){
    int j = j0 + jj;
    const float* wr = Wip + j*32;               // wave-uniform -> s_loads
    float acc = 0.0f;
    #pragma unroll
    for (int c=0;c<32;++c) acc += xv[c]*wr[c];
    size_t o = ((size_t)(bi*64 + (j & 63)))*4096 + l0 + lane;
    if (j < 64) xm_pre[o] = acc;
    else        sz[o] = acc * sigmoid_f(acc);
  }
}

// ---------------- depthwise causal conv1d k=4 + bias + silu ----------------
__global__ __launch_bounds__(256) void dwconv_silu_k(const float* __restrict__ xin,
    const float* __restrict__ w, const float* __restrict__ bias, float* __restrict__ xout)
{
  const int bd = blockIdx.x, d = bd & 63;
  const float* p = xin + (size_t)bd*SEQL;
  float* q = xout + (size_t)bd*SEQL;
  const float w0=w[d*4], w1=w[d*4+1], w2=w[d*4+2], w3=w[d*4+3], bv=bias[d];
  for (int l=threadIdx.x; l<SEQL; l+=256){
    float x0 = (l>=3)? p[l-3] : 0.0f;
    float x1 = (l>=2)? p[l-2] : 0.0f;
    float x2 = (l>=1)? p[l-1] : 0.0f;
    float x3 = p[l];
    float a = x0*w0 + x1*w1 + x2*w2 + x3*w3 + bv;
    q[l] = a * sigmoid_f(a);
  }
}

// -------- x_proj (64->66) + dt_proj (2->64) + softplus; B/C split ----------
__global__ __launch_bounds__(256) void xproj_k(const float* __restrict__ xm2,
    const float* __restrict__ Wxp, const float* __restrict__ Wdt,
    const float* __restrict__ bdt, float* __restrict__ delta,
    float* __restrict__ Bm, float* __restrict__ Cm)
{
  __shared__ float xt[64][65];
  __shared__ float xd[64][67];
  const int tid = threadIdx.x, lane = tid & 63, ty = tid >> 6;
  const int bi = blockIdx.x >> 6;
  const int l0 = (blockIdx.x & 63) << 6;
  for (int dd=ty; dd<64; dd+=4)
    xt[dd][lane] = xm2[((size_t)(bi*64+dd))*SEQL + l0 + lane];
  __syncthreads();
  float xv[64];
  #pragma unroll
  for (int d2=0; d2<64; ++d2) xv[d2] = xt[d2][lane];
  for (int j=ty; j<66; j+=4){
    const float* wr = Wxp + j*64;
    float acc = 0.0f;
    #pragma unroll
    for (int d2=0; d2<64; ++d2) acc += xv[d2]*wr[d2];
    xd[lane][j] = acc;
  }
  __syncthreads();
  // delta = softplus(dt @ Wdt^T + bdt)  (matches np.logaddexp(x,0))
  float dt0 = xd[lane][0], dt1 = xd[lane][1];
  #pragma unroll
  for (int k=0;k<16;++k){
    int d2 = ty*16 + k;
    float v = dt0*Wdt[d2*2] + dt1*Wdt[d2*2+1] + bdt[d2];
    float sp = fmaxf(v,0.0f) + log1pf(expf(-fabsf(v)));
    delta[((size_t)(bi*64+d2))*SEQL + l0 + lane] = sp;
  }
  // B (n 0..31) / C (n 0..31) in (b,l,n) layout, float4 stores
  const int half = ty & 1, which = ty >> 1;
  float* dst = which ? Cm : Bm;
  size_t base = ((size_t)bi*SEQL + l0 + lane)*32 + half*16;
  const int src0 = 2 + which*32 + half*16;
  #pragma unroll
  for (int k=0;k<16;k+=4){
    float4 f; f.x = xd[lane][src0+k]; f.y = xd[lane][src0+k+1];
    f.z = xd[lane][src0+k+2]; f.w = xd[lane][src0+k+3];
    *(float4*)(dst + base + k) = f;
  }
}

// ---------------- selective scan: chunked 2-pass + gate --------------------
// block = (b,d); 1024 thr = 32 n-lanes x 32 chunks of 128 steps
__global__ __launch_bounds__(1024) void scan_k(const float* __restrict__ delta,
    const float* __restrict__ xssm, const float* __restrict__ Bm,
    const float* __restrict__ Cm, const float* __restrict__ A_log,
    const float* __restrict__ Dp, const float* __restrict__ sz,
    float* __restrict__ yt)
{
  __shared__ float sA[32][32];
  __shared__ float sH[32][32];
  const int tid = threadIdx.x;
  const int n = tid & 31, chunk = tid >> 5;
  const int bd = blockIdx.x, b = bd >> 6, d = bd & 63;
  const float* del = delta + (size_t)bd*SEQL;
  const float* xp  = xssm  + (size_t)bd*SEQL;
  const float* szp = sz    + (size_t)bd*SEQL;
  const float* Bp  = Bm + (size_t)b*SEQL*32;
  const float* Cp  = Cm + (size_t)b*SEQL*32;
  const float Av = -expf(A_log[d*32+n]);
  const float Dv = Dp[d];
  const int l0 = chunk*128;
  // pass 1: chunk summaries (prod a, h_end) -- mul/add kept unfused to track np
  float h = 0.0f, aP = 1.0f;
  for (int i=0;i<128;++i){
    int l = l0 + i;
    float dl = del[l];
    float a  = expf(__fmul_rn(dl, Av));
    float bx = __fmul_rn(__fmul_rn(dl, Bp[l*32+n]), xp[l]);
    h  = __fadd_rn(__fmul_rn(a,h), bx);
    aP *= a;
  }
  sA[chunk][n] = aP; sH[chunk][n] = h;
  __syncthreads();
  if (tid < 32){                                 // sequential combine, 32 chains
    float hrun = 0.0f;
    #pragma unroll
    for (int c=0;c<32;++c){
      float ac = sA[c][tid], hc = sH[c][tid];
      sA[c][tid] = hrun;                          // exclusive prefix
      hrun = __fadd_rn(__fmul_rn(ac,hrun), hc);
    }
  }
  __syncthreads();
  // pass 2: rescan with prefix, reduce over n, gate, store (b,d,l)
  h = sA[chunk][n];
  for (int i=0;i<128;++i){
    int l = l0 + i;
    float dl = del[l];
    float a  = expf(__fmul_rn(dl, Av));
    float xl = xp[l];
    float bx = __fmul_rn(__fmul_rn(dl, Bp[l*32+n]), xl);
    h = __fadd_rn(__fmul_rn(a,h), bx);
    float v = __fmul_rn(h, Cp[l*32+n]);
    v += __shfl_xor(v,16); v += __shfl_xor(v,8); v += __shfl_xor(v,4);
    v += __shfl_xor(v,2);  v += __shfl_xor(v,1);   // stays within 32-lane half
    if (n==0){
      float yv = v + xl*Dv;
      yt[(size_t)bd*SEQL + l] = yv * szp[l];
    }
  }
}

// ---------------- out_proj (64->32) into (b,c,l) = NCHW image --------------
__global__ __launch_bounds__(256) void outproj_k(const float* __restrict__ yt,
    const float* __restrict__ Wout, float* __restrict__ ym)
{
  __shared__ float ys[64][65];
  const int tid = threadIdx.x, lane = tid & 63, ty = tid >> 6;
  const int bi = blockIdx.x >> 6;
  const int l0 = (blockIdx.x & 63) << 6;
  for (int dd=ty; dd<64; dd+=4)
    ys[dd][lane] = yt[((size_t)(bi*64+dd))*SEQL + l0 + lane];
  __syncthreads();
  float yv[64];
  #pragma unroll
  for (int d2=0; d2<64; ++d2) yv[d2] = ys[d2][lane];
  #pragma unroll
  for (int jj=0;jj<8;++jj){
    int j = ty*8 + jj;
    const float* wr = Wout + j*64;
    float acc = 0.0f;
    #pragma unroll
    for (int d2=0; d2<64; ++d2) acc += yv[d2]*wr[d2];
    ym[((size_t)(bi*32+j))*SEQL + l0 + lane] = acc;
  }
}

extern "C" void kernel_launch(void* const* d_in, const int* in_sizes, int n_in,
                              void* d_out, int out_size, void* d_ws, size_t ws_size,
                              hipStream_t stream) {
  const float* x        = (const float*)d_in[0];
  const float* conv1_w  = (const float*)d_in[1];
  const float* conv1_b  = (const float*)d_in[2];
  const float* conv2_w  = (const float*)d_in[3];
  const float* conv2_b  = (const float*)d_in[4];
  const float* ln_g     = (const float*)d_in[5];
  const float* ln_b     = (const float*)d_in[6];
  const float* in_proj_w= (const float*)d_in[7];
  const float* conv1d_w = (const float*)d_in[8];
  const float* conv1d_b = (const float*)d_in[9];
  const float* x_proj_w = (const float*)d_in[10];
  const float* dt_proj_w= (const float*)d_in[11];
  const float* dt_proj_b= (const float*)d_in[12];
  const float* A_log    = (const float*)d_in[13];
  const float* Dp       = (const float*)d_in[14];
  const float* out_proj_w=(const float*)d_in[15];
  const float* smooth_w = (const float*)d_in[16];
  const float* smooth_b = (const float*)d_in[17];
  float* out = (float*)d_out;

  float* ws = (float*)d_ws;
  float* t      = ws;                 // (4,64,64,64)  1048576
  float* x2     = t      + 1048576;   // (4,32,4096)    524288
  float* xm_pre = x2     + 524288;    // (4,64,4096)   1048576
  float* xm2    = xm_pre + 1048576;   // (4,64,4096)   1048576
  float* szb    = xm2    + 1048576;   // (4,64,4096)   1048576
  float* dlt    = szb    + 1048576;   // (4,64,4096)   1048576
  float* Bmat   = dlt    + 1048576;   // (4,4096,32)    524288
  float* Cmat   = Bmat   + 524288;    // (4,4096,32)    524288
  float* yt     = Cmat   + 524288;    // (4,64,4096)   1048576
  float* ym     = yt     + 1048576;   // (4,32,4096)    524288

  dim3 cblk(64,4);
  conv3x3_k<32,true ,false><<<dim3(4,64,4), cblk, 0, stream>>>(x,  conv1_w, conv1_b, nullptr, t);
  conv3x3_k<64,false,true ><<<dim3(4,32,4), cblk, 0, stream>>>(t,  conv2_w, conv2_b, x,       x2);
  ln_inproj_k <<<256, 256, 0, stream>>>(x2, ln_g, ln_b, in_proj_w, xm_pre, szb);
  dwconv_silu_k<<<256, 256, 0, stream>>>(xm_pre, conv1d_w, conv1d_b, xm2);
  xproj_k     <<<256, 256, 0, stream>>>(xm2, x_proj_w, dt_proj_w, dt_proj_b, dlt, Bmat, Cmat);
  scan_k      <<<256,1024, 0, stream>>>(dlt, xm2, Bmat, Cmat, A_log, Dp, szb, yt);
  outproj_k   <<<256, 256, 0, stream>>>(yt, out_proj_w, ym);
  conv3x3_k<32,false,false><<<dim3(4,32,4), cblk, 0, stream>>>(ym, smooth_w, smooth_b, nullptr, out);
}

// Round 2
// 341.284 us; speedup vs baseline: 1.5188x; 1.5188x over previous
//
#include <hip/hip_runtime.h>
#include <math.h>

#define SEQL 4096
#define L2E 1.44269504088896340736f

#if defined(__has_builtin)
#if __has_builtin(__builtin_amdgcn_exp2f)
#define FAST_EXP2(x) __builtin_amdgcn_exp2f(x)
#endif
#endif
#ifndef FAST_EXP2
#define FAST_EXP2(x) exp2f(x)
#endif

__device__ __forceinline__ float sigmoid_f(float x){ return 1.0f/(1.0f+expf(-x)); }

// ---------------- conv 3x3, pad 1, 64x64 image, 2 rows/thread ----------------
template<int CI, bool RELU, bool RES>
__global__ __launch_bounds__(256) void conv3x3_k(const float* __restrict__ in,
    const float* __restrict__ wgt, const float* __restrict__ bias,
    const float* __restrict__ res, float* __restrict__ out)
{
  const int lane = threadIdx.x;                 // w, 0..63 (full wave = one row)
  const int h0   = blockIdx.x*8 + threadIdx.y*2;
  const int co   = blockIdx.y;
  const int b    = blockIdx.z;
  const int CO   = gridDim.y;
  float bv = bias[co];
  float acc0 = bv, acc1 = bv;
  const float* wp = wgt + (size_t)co*CI*9;
  for (int ci=0; ci<CI; ++ci){
    const float* p = in + ((size_t)(b*CI+ci))*4096;
    float w_[9];
    #pragma unroll
    for (int k=0;k<9;++k) w_[k] = wp[ci*9+k];
    #pragma unroll
    for (int j=0;j<4;++j){
      int hh = h0 - 1 + j;                      // wave-uniform branch
      float mid = (hh>=0 && hh<64) ? p[hh*64+lane] : 0.0f;
      float lv = __shfl_up(mid,1);   if (lane==0)  lv = 0.0f;
      float rv = __shfl_down(mid,1); if (lane==63) rv = 0.0f;
      if (j<3)  acc0 += lv*w_[j*3+0] + mid*w_[j*3+1] + rv*w_[j*3+2];
      if (j>=1) acc1 += lv*w_[(j-1)*3+0] + mid*w_[(j-1)*3+1] + rv*w_[(j-1)*3+2];
    }
  }
  size_t ob = ((size_t)(b*CO+co))*4096 + (size_t)h0*64 + lane;
  float v0 = acc0, v1 = acc1;
  if constexpr (RES){ v0 += res[ob]; v1 += res[ob+64]; }
  if constexpr (RELU){ v0 = fmaxf(v0,0.0f); v1 = fmaxf(v1,0.0f); }
  out[ob] = v0; out[ob+64] = v1;
}

// ---------------- LayerNorm(32) + in_proj (32->128) + silu on z half --------
__global__ __launch_bounds__(512) void ln_inproj_k(const float* __restrict__ x2,
    const float* __restrict__ g, const float* __restrict__ be,
    const float* __restrict__ Wip, float* __restrict__ xm_pre, float* __restrict__ sz)
{
  __shared__ float xn[64][36];
  const int tid = threadIdx.x, lane = tid & 63, ty = tid >> 6;
  const int bi = blockIdx.x >> 6;
  const int l0 = (blockIdx.x & 63) << 6;
  if (ty == 0){
    const float* row = x2 + (size_t)bi*131072 + (size_t)(l0+lane)*32;
    float v[32];
    #pragma unroll
    for (int c=0;c<32;c+=4){
      float4 f = *(const float4*)(row + c);
      v[c]=f.x; v[c+1]=f.y; v[c+2]=f.z; v[c+3]=f.w;
    }
    float p[8];
    #pragma unroll
    for (int j2=0;j2<8;++j2) p[j2]=v[j2];
    #pragma unroll
    for (int i=8;i<32;i+=8){
      #pragma unroll
      for (int j2=0;j2<8;++j2) p[j2]+=v[i+j2];
    }
    float mu = (((p[0]+p[1])+(p[2]+p[3]))+((p[4]+p[5])+(p[6]+p[7]))) * 0.03125f;
    float q[8];
    #pragma unroll
    for (int j2=0;j2<8;++j2){ float dd=v[j2]-mu; q[j2]=dd*dd; }
    #pragma unroll
    for (int i=8;i<32;i+=8){
      #pragma unroll
      for (int j2=0;j2<8;++j2){ float dd=v[i+j2]-mu; q[j2]+=dd*dd; }
    }
    float var = (((q[0]+q[1])+(q[2]+q[3]))+((q[4]+q[5])+(q[6]+q[7]))) * 0.03125f;
    float rstd = 1.0f / sqrtf(var + 1e-5f);
    #pragma unroll
    for (int c=0;c<32;++c) xn[lane][c] = (v[c]-mu)*rstd*g[c] + be[c];
  }
  __syncthreads();
  float xv[32];
  #pragma unroll
  for (int c=0;c<32;c+=4){
    float4 f = *(const float4*)(&xn[lane][c]);
    xv[c]=f.x; xv[c+1]=f.y; xv[c+2]=f.z; xv[c+3]=f.w;
  }
  #pragma unroll
  for (int jj=0;jj<16;++jj){
    int j = (ty<<4) + jj;
    const float* wr = Wip + j*32;
    float acc = 0.0f;
    #pragma unroll
    for (int c=0;c<32;++c) acc = fmaf(xv[c], wr[c], acc);
    size_t o = ((size_t)(bi*64 + (j & 63)))*SEQL + l0 + lane;
    if (j < 64) xm_pre[o] = acc;
    else        sz[o] = acc * sigmoid_f(acc);
  }
}

// ---- fused: depthwise causal conv1d+silu, x_proj (64->66), dt_proj+softplus, B/C split
__global__ __launch_bounds__(512) void xproj_k(const float* __restrict__ xm_pre,
    const float* __restrict__ cw, const float* __restrict__ cb,
    const float* __restrict__ Wxp, const float* __restrict__ Wdt,
    const float* __restrict__ bdt, float* __restrict__ xm2,
    float* __restrict__ delta, float* __restrict__ Bm, float* __restrict__ Cm)
{
  __shared__ float xs[64][68];   // xs[d][c] = xm_pre[l0-3+c], c in 0..66
  __shared__ float xt[64][68];   // xt[l][d] = silu(conv) transposed
  __shared__ float xd[64][68];   // xd[l][j], j in 0..65
  const int tid = threadIdx.x, lane = tid & 63, ty = tid >> 6;
  const int bi = blockIdx.x >> 6;
  const int l0 = (blockIdx.x & 63) << 6;
  for (int r=ty; r<64; r+=8){
    const float* src = xm_pre + ((size_t)(bi*64+r))*SEQL + l0;
    float v = 0.0f;
    if (l0 + lane - 3 >= 0) v = src[lane-3];
    xs[r][lane] = v;
    if (lane < 3) xs[r][64+lane] = src[61+lane];
  }
  __syncthreads();
  for (int r=ty; r<64; r+=8){
    float w0=cw[r*4], w1=cw[r*4+1], w2=cw[r*4+2], w3=cw[r*4+3], bv=cb[r];
    float a = xs[r][lane]*w0 + xs[r][lane+1]*w1 + xs[r][lane+2]*w2 + xs[r][lane+3]*w3 + bv;
    float s = a * sigmoid_f(a);
    xt[lane][r] = s;
    xm2[((size_t)(bi*64+r))*SEQL + l0 + lane] = s;
  }
  __syncthreads();
  float xv[64];
  #pragma unroll
  for (int c=0;c<64;c+=4){
    float4 f = *(const float4*)(&xt[lane][c]);
    xv[c]=f.x; xv[c+1]=f.y; xv[c+2]=f.z; xv[c+3]=f.w;
  }
  for (int j=ty; j<66; j+=8){
    const float* wr = Wxp + j*64;
    float acc = 0.0f;
    #pragma unroll
    for (int c=0;c<64;++c) acc = fmaf(xv[c], wr[c], acc);
    xd[lane][j] = acc;
  }
  __syncthreads();
  float dt0 = xd[lane][0], dt1 = xd[lane][1];
  #pragma unroll
  for (int k=0;k<8;++k){
    int d2 = ty*8 + k;
    float v = dt0*Wdt[d2*2] + dt1*Wdt[d2*2+1] + bdt[d2];
    float sp = fmaxf(v,0.0f) + log1pf(expf(-fabsf(v)));
    delta[((size_t)(bi*64+d2))*SEQL + l0 + lane] = sp;
  }
  const int which = ty >> 2, gq = ty & 3;
  float* dst = which ? Cm : Bm;
  size_t base = ((size_t)bi*SEQL + l0 + lane)*32 + gq*8;
  const int s0 = 2 + which*32 + gq*8;
  float4 f0, f1;
  f0.x = xd[lane][s0+0]; f0.y = xd[lane][s0+1]; f0.z = xd[lane][s0+2]; f0.w = xd[lane][s0+3];
  f1.x = xd[lane][s0+4]; f1.y = xd[lane][s0+5]; f1.z = xd[lane][s0+6]; f1.w = xd[lane][s0+7];
  *(float4*)(dst + base)     = f0;
  *(float4*)(dst + base + 4) = f1;
}

// ---------------- selective scan: 3-kernel chunked scan, chunk=64 ----------
// thread = (bd, chunk, n); 2048 blocks x 256 thr for pass1/pass2
__global__ __launch_bounds__(256) void scan_p1(const float* __restrict__ dlt,
    const float* __restrict__ xssm, const float* __restrict__ Bm,
    const float* __restrict__ A_log, float* __restrict__ cA, float* __restrict__ cH)
{
  const int tid = threadIdx.x;
  const int n = tid & 31;
  const int chunk = (blockIdx.x & 7)*8 + (tid >> 5);
  const int bd = blockIdx.x >> 3;
  const int b = bd >> 6, d = bd & 63;
  const int l0 = chunk << 6;
  const float Av2 = -expf(A_log[d*32+n]) * L2E;
  const float* del = dlt  + (size_t)bd*SEQL + l0;
  const float* xp  = xssm + (size_t)bd*SEQL + l0;
  const float* Bp  = Bm + ((size_t)b*SEQL + l0)*32 + n;
  float h = 0.0f, aP = 1.0f;
  #pragma unroll 4
  for (int i0=0;i0<64;i0+=4){
    float4 d4 = *(const float4*)(del+i0);
    float4 x4 = *(const float4*)(xp +i0);
    float b0 = Bp[(i0+0)*32], b1 = Bp[(i0+1)*32], b2 = Bp[(i0+2)*32], b3 = Bp[(i0+3)*32];
    float a0 = FAST_EXP2(d4.x*Av2); h = fmaf(a0,h, d4.x*b0*x4.x); aP *= a0;
    float a1 = FAST_EXP2(d4.y*Av2); h = fmaf(a1,h, d4.y*b1*x4.y); aP *= a1;
    float a2 = FAST_EXP2(d4.z*Av2); h = fmaf(a2,h, d4.z*b2*x4.z); aP *= a2;
    float a3 = FAST_EXP2(d4.w*Av2); h = fmaf(a3,h, d4.w*b3*x4.w); aP *= a3;
  }
  int idx = (bd*64+chunk)*32 + n;
  cA[idx] = aP; cH[idx] = h;
}

__global__ __launch_bounds__(128) void scan_comb(const float* __restrict__ cA,
    float* __restrict__ cH)
{
  const int gid = blockIdx.x*128 + threadIdx.x;   // 8192 = 256 bd x 32 n
  const int n = gid & 31, bd = gid >> 5;
  const size_t base = (size_t)bd*64*32 + n;
  float hrun = 0.0f;
  #pragma unroll 8
  for (int c=0;c<64;++c){
    float ac = cA[base + c*32];
    float hc = cH[base + c*32];
    cH[base + c*32] = hrun;                        // exclusive prefix
    hrun = fmaf(ac, hrun, hc);
  }
}

__global__ __launch_bounds__(256) void scan_p2(const float* __restrict__ dlt,
    const float* __restrict__ xssm, const float* __restrict__ Bm,
    const float* __restrict__ Cm, const float* __restrict__ A_log,
    const float* __restrict__ Dp, const float* __restrict__ sz,
    const float* __restrict__ cH, float* __restrict__ yt)
{
  const int tid = threadIdx.x;
  const int n = tid & 31;
  const int chunk = (blockIdx.x & 7)*8 + (tid >> 5);
  const int bd = blockIdx.x >> 3;
  const int b = bd >> 6, d = bd & 63;
  const int l0 = chunk << 6;
  const float Av2 = -expf(A_log[d*32+n]) * L2E;
  const float Dv = Dp[d];
  const float* del = dlt  + (size_t)bd*SEQL + l0;
  const float* xp  = xssm + (size_t)bd*SEQL + l0;
  const float* szp = sz   + (size_t)bd*SEQL + l0;
  const float* Bp  = Bm + ((size_t)b*SEQL + l0)*32 + n;
  const float* Cp  = Cm + ((size_t)b*SEQL + l0)*32 + n;
  float* yp = yt + (size_t)bd*SEQL + l0;
  float h = cH[(bd*64+chunk)*32 + n];
  #pragma unroll 2
  for (int i0=0;i0<64;i0+=4){
    float4 d4 = *(const float4*)(del+i0);
    float4 x4 = *(const float4*)(xp +i0);
    float4 s4 = *(const float4*)(szp+i0);
    float b0 = Bp[(i0+0)*32], b1 = Bp[(i0+1)*32], b2 = Bp[(i0+2)*32], b3 = Bp[(i0+3)*32];
    float c0 = Cp[(i0+0)*32], c1 = Cp[(i0+1)*32], c2 = Cp[(i0+2)*32], c3 = Cp[(i0+3)*32];
    float a0 = FAST_EXP2(d4.x*Av2); h = fmaf(a0,h, d4.x*b0*x4.x);
    float v0 = h*c0;
    float a1 = FAST_EXP2(d4.y*Av2); h = fmaf(a1,h, d4.y*b1*x4.y);
    float v1 = h*c1;
    float a2 = FAST_EXP2(d4.z*Av2); h = fmaf(a2,h, d4.z*b2*x4.z);
    float v2 = h*c2;
    float a3 = FAST_EXP2(d4.w*Av2); h = fmaf(a3,h, d4.w*b3*x4.w);
    float v3 = h*c3;
    v0 += __shfl_xor(v0,16); v0 += __shfl_xor(v0,8); v0 += __shfl_xor(v0,4);
    v0 += __shfl_xor(v0,2);  v0 += __shfl_xor(v0,1);
    v1 += __shfl_xor(v1,16); v1 += __shfl_xor(v1,8); v1 += __shfl_xor(v1,4);
    v1 += __shfl_xor(v1,2);  v1 += __shfl_xor(v1,1);
    v2 += __shfl_xor(v2,16); v2 += __shfl_xor(v2,8); v2 += __shfl_xor(v2,4);
    v2 += __shfl_xor(v2,2);  v2 += __shfl_xor(v2,1);
    v3 += __shfl_xor(v3,16); v3 += __shfl_xor(v3,8); v3 += __shfl_xor(v3,4);
    v3 += __shfl_xor(v3,2);  v3 += __shfl_xor(v3,1);
    if (n==0){
      yp[i0+0] = fmaf(x4.x, Dv, v0) * s4.x;
      yp[i0+1] = fmaf(x4.y, Dv, v1) * s4.y;
      yp[i0+2] = fmaf(x4.z, Dv, v2) * s4.z;
      yp[i0+3] = fmaf(x4.w, Dv, v3) * s4.w;
    }
  }
}

// ---------------- out_proj (64->32) into (b,c,l) = NCHW image --------------
__global__ __launch_bounds__(512) void outproj_k(const float* __restrict__ yt,
    const float* __restrict__ Wout, float* __restrict__ ym)
{
  __shared__ float ys[64][68];    // ys[l][d]
  const int tid = threadIdx.x, lane = tid & 63, ty = tid >> 6;
  const int bi = blockIdx.x >> 6;
  const int l0 = (blockIdx.x & 63) << 6;
  for (int r=ty; r<64; r+=8)
    ys[lane][r] = yt[((size_t)(bi*64+r))*SEQL + l0 + lane];
  __syncthreads();
  float yv[64];
  #pragma unroll
  for (int c=0;c<64;c+=4){
    float4 f = *(const float4*)(&ys[lane][c]);
    yv[c]=f.x; yv[c+1]=f.y; yv[c+2]=f.z; yv[c+3]=f.w;
  }
  #pragma unroll
  for (int jj=0;jj<4;++jj){
    int j = ty*4 + jj;
    const float* wr = Wout + j*64;
    float acc = 0.0f;
    #pragma unroll
    for (int c=0;c<64;++c) acc = fmaf(yv[c], wr[c], acc);
    ym[((size_t)(bi*32+j))*SEQL + l0 + lane] = acc;
  }
}

extern "C" void kernel_launch(void* const* d_in, const int* in_sizes, int n_in,
                              void* d_out, int out_size, void* d_ws, size_t ws_size,
                              hipStream_t stream) {
  const float* x        = (const float*)d_in[0];
  const float* conv1_w  = (const float*)d_in[1];
  const float* conv1_b  = (const float*)d_in[2];
  const float* conv2_w  = (const float*)d_in[3];
  const float* conv2_b  = (const float*)d_in[4];
  const float* ln_g     = (const float*)d_in[5];
  const float* ln_b     = (const float*)d_in[6];
  const float* in_proj_w= (const float*)d_in[7];
  const float* conv1d_w = (const float*)d_in[8];
  const float* conv1d_b = (const float*)d_in[9];
  const float* x_proj_w = (const float*)d_in[10];
  const float* dt_proj_w= (const float*)d_in[11];
  const float* dt_proj_b= (const float*)d_in[12];
  const float* A_log    = (const float*)d_in[13];
  const float* Dp       = (const float*)d_in[14];
  const float* out_proj_w=(const float*)d_in[15];
  const float* smooth_w = (const float*)d_in[16];
  const float* smooth_b = (const float*)d_in[17];
  float* out = (float*)d_out;

  float* ws = (float*)d_ws;
  float* t      = ws;                 // (4,64,64,64)  1048576  (free after conv2)
  float* x2     = t      + 1048576;   // (4,32,4096)    524288
  float* xm_pre = x2     + 524288;    // (4,64,4096)   1048576
  float* xm2    = xm_pre + 1048576;   // (4,64,4096)   1048576
  float* szb    = xm2    + 1048576;   // (4,64,4096)   1048576
  float* dlt    = szb    + 1048576;   // (4,64,4096)   1048576
  float* Bmat   = dlt    + 1048576;   // (4,4096,32)    524288
  float* Cmat   = Bmat   + 524288;    // (4,4096,32)    524288
  float* yt     = Cmat   + 524288;    // (4,64,4096)   1048576
  float* ym     = yt     + 1048576;   // (4,32,4096)    524288
  float* cA     = t;                  // (256,64,32)    524288 (aliases t)
  float* cH     = t + 524288;         // (256,64,32)    524288 (aliases t)

  dim3 cblk(64,4);
  conv3x3_k<32,true ,false><<<dim3(8,64,4), cblk, 0, stream>>>(x,  conv1_w, conv1_b, nullptr, t);
  conv3x3_k<64,false,true ><<<dim3(8,32,4), cblk, 0, stream>>>(t,  conv2_w, conv2_b, x,       x2);
  ln_inproj_k <<<256, 512, 0, stream>>>(x2, ln_g, ln_b, in_proj_w, xm_pre, szb);
  xproj_k     <<<256, 512, 0, stream>>>(xm_pre, conv1d_w, conv1d_b, x_proj_w, dt_proj_w, dt_proj_b,
                                        xm2, dlt, Bmat, Cmat);
  scan_p1     <<<2048, 256, 0, stream>>>(dlt, xm2, Bmat, A_log, cA, cH);
  scan_comb   <<<64,   128, 0, stream>>>(cA, cH);
  scan_p2     <<<2048, 256, 0, stream>>>(dlt, xm2, Bmat, Cmat, A_log, Dp, szb, cH, yt);
  outproj_k   <<<256, 512, 0, stream>>>(yt, out_proj_w, ym);
  conv3x3_k<32,false,false><<<dim3(8,32,4), cblk, 0, stream>>>(ym, smooth_w, smooth_b, nullptr, out);
}

// Round 3
// 316.764 us; speedup vs baseline: 1.6363x; 1.0774x over previous
//
#include <hip/hip_runtime.h>
#include <math.h>

#define SEQL 4096
#define L2E 1.44269504088896340736f

#if defined(__has_builtin)
#if __has_builtin(__builtin_amdgcn_exp2f)
#define FAST_EXP2(x) __builtin_amdgcn_exp2f(x)
#endif
#endif
#ifndef FAST_EXP2
#define FAST_EXP2(x) exp2f(x)
#endif

__device__ __forceinline__ float sigmoid_f(float x){ return 1.0f/(1.0f+expf(-x)); }

// ---------------- conv 3x3, pad 1, 64x64 image ----------------
// thread = (w=lane, one output row h, COPT output channels). 2 waves/SIMD grid.
template<int CI, int CO, int COPT, bool RELU, bool RES>
__global__ __launch_bounds__(256) void conv3x3_k(const float* __restrict__ in,
    const float* __restrict__ wgt, const float* __restrict__ bias,
    const float* __restrict__ res, float* __restrict__ out)
{
  const int lane = threadIdx.x;                 // w, 0..63
  const int h    = blockIdx.x*4 + threadIdx.y;  // output row
  const int co0  = blockIdx.y*COPT;
  const int b    = blockIdx.z;
  float acc[COPT];
  #pragma unroll
  for (int u=0;u<COPT;++u) acc[u] = bias[co0+u];
  #pragma unroll 2
  for (int ci=0; ci<CI; ++ci){
    const float* p = in + ((size_t)(b*CI+ci))*4096;
    float mid[3], lv[3], rv[3];
    #pragma unroll
    for (int j=0;j<3;++j){
      int hh = h - 1 + j;                       // wave-uniform branch
      mid[j] = (hh>=0 && hh<64) ? p[hh*64+lane] : 0.0f;
      lv[j] = __shfl_up(mid[j],1);   if (lane==0)  lv[j] = 0.0f;
      rv[j] = __shfl_down(mid[j],1); if (lane==63) rv[j] = 0.0f;
    }
    #pragma unroll
    for (int u=0;u<COPT;++u){
      const float* wp = wgt + ((size_t)(co0+u)*CI + ci)*9;   // uniform -> s_load
      #pragma unroll
      for (int j=0;j<3;++j)
        acc[u] += lv[j]*wp[j*3+0] + mid[j]*wp[j*3+1] + rv[j]*wp[j*3+2];
    }
  }
  #pragma unroll
  for (int u=0;u<COPT;++u){
    size_t ob = ((size_t)(b*CO+co0+u))*4096 + (size_t)h*64 + lane;
    float v = acc[u];
    if constexpr (RES)  v += res[ob];
    if constexpr (RELU) v = fmaxf(v, 0.0f);
    out[ob] = v;
  }
}

// ---------------- LayerNorm(32) + in_proj (32->128) + silu on z half --------
__global__ __launch_bounds__(512) void ln_inproj_k(const float* __restrict__ x2,
    const float* __restrict__ g, const float* __restrict__ be,
    const float* __restrict__ Wip, float* __restrict__ xm_pre, float* __restrict__ sz)
{
  __shared__ float xn[64][36];
  const int tid = threadIdx.x, lane = tid & 63, ty = tid >> 6;
  const int bi = blockIdx.x >> 6;
  const int l0 = (blockIdx.x & 63) << 6;
  if (ty == 0){
    const float* row = x2 + (size_t)bi*131072 + (size_t)(l0+lane)*32;
    float v[32];
    #pragma unroll
    for (int c=0;c<32;c+=4){
      float4 f = *(const float4*)(row + c);
      v[c]=f.x; v[c+1]=f.y; v[c+2]=f.z; v[c+3]=f.w;
    }
    float p[8];
    #pragma unroll
    for (int j2=0;j2<8;++j2) p[j2]=v[j2];
    #pragma unroll
    for (int i=8;i<32;i+=8){
      #pragma unroll
      for (int j2=0;j2<8;++j2) p[j2]+=v[i+j2];
    }
    float mu = (((p[0]+p[1])+(p[2]+p[3]))+((p[4]+p[5])+(p[6]+p[7]))) * 0.03125f;
    float q[8];
    #pragma unroll
    for (int j2=0;j2<8;++j2){ float dd=v[j2]-mu; q[j2]=dd*dd; }
    #pragma unroll
    for (int i=8;i<32;i+=8){
      #pragma unroll
      for (int j2=0;j2<8;++j2){ float dd=v[i+j2]-mu; q[j2]+=dd*dd; }
    }
    float var = (((q[0]+q[1])+(q[2]+q[3]))+((q[4]+q[5])+(q[6]+q[7]))) * 0.03125f;
    float rstd = 1.0f / sqrtf(var + 1e-5f);
    #pragma unroll
    for (int c=0;c<32;++c) xn[lane][c] = (v[c]-mu)*rstd*g[c] + be[c];
  }
  __syncthreads();
  float xv[32];
  #pragma unroll
  for (int c=0;c<32;c+=4){
    float4 f = *(const float4*)(&xn[lane][c]);
    xv[c]=f.x; xv[c+1]=f.y; xv[c+2]=f.z; xv[c+3]=f.w;
  }
  #pragma unroll
  for (int jj=0;jj<16;++jj){
    int j = (ty<<4) + jj;
    const float* wr = Wip + j*32;
    float acc = 0.0f;
    #pragma unroll
    for (int c=0;c<32;++c) acc = fmaf(xv[c], wr[c], acc);
    size_t o = ((size_t)(bi*64 + (j & 63)))*SEQL + l0 + lane;
    if (j < 64) xm_pre[o] = acc;
    else        sz[o] = acc * sigmoid_f(acc);
  }
}

// ---- fused: depthwise causal conv1d+silu, x_proj (64->66), dt_proj+softplus, B/C split
__global__ __launch_bounds__(512) void xproj_k(const float* __restrict__ xm_pre,
    const float* __restrict__ cw, const float* __restrict__ cb,
    const float* __restrict__ Wxp, const float* __restrict__ Wdt,
    const float* __restrict__ bdt, float* __restrict__ xm2,
    float* __restrict__ delta, float* __restrict__ Bm, float* __restrict__ Cm)
{
  __shared__ float xs[64][68];   // xs[d][c] = xm_pre[l0-3+c], c in 0..66
  __shared__ float xt[64][68];   // xt[l][d] = silu(conv) transposed
  __shared__ float xd[64][68];   // xd[l][j], j in 0..65
  const int tid = threadIdx.x, lane = tid & 63, ty = tid >> 6;
  const int bi = blockIdx.x >> 6;
  const int l0 = (blockIdx.x & 63) << 6;
  for (int r=ty; r<64; r+=8){
    const float* src = xm_pre + ((size_t)(bi*64+r))*SEQL + l0;
    float v = 0.0f;
    if (l0 + lane - 3 >= 0) v = src[lane-3];
    xs[r][lane] = v;
    if (lane < 3) xs[r][64+lane] = src[61+lane];
  }
  __syncthreads();
  for (int r=ty; r<64; r+=8){
    float w0=cw[r*4], w1=cw[r*4+1], w2=cw[r*4+2], w3=cw[r*4+3], bv=cb[r];
    float a = xs[r][lane]*w0 + xs[r][lane+1]*w1 + xs[r][lane+2]*w2 + xs[r][lane+3]*w3 + bv;
    float s = a * sigmoid_f(a);
    xt[lane][r] = s;
    xm2[((size_t)(bi*64+r))*SEQL + l0 + lane] = s;
  }
  __syncthreads();
  float xv[64];
  #pragma unroll
  for (int c=0;c<64;c+=4){
    float4 f = *(const float4*)(&xt[lane][c]);
    xv[c]=f.x; xv[c+1]=f.y; xv[c+2]=f.z; xv[c+3]=f.w;
  }
  for (int j=ty; j<66; j+=8){
    const float* wr = Wxp + j*64;
    float acc = 0.0f;
    #pragma unroll
    for (int c=0;c<64;++c) acc = fmaf(xv[c], wr[c], acc);
    xd[lane][j] = acc;
  }
  __syncthreads();
  float dt0 = xd[lane][0], dt1 = xd[lane][1];
  #pragma unroll
  for (int k=0;k<8;++k){
    int d2 = ty*8 + k;
    float v = dt0*Wdt[d2*2] + dt1*Wdt[d2*2+1] + bdt[d2];
    float sp = fmaxf(v,0.0f) + log1pf(expf(-fabsf(v)));
    delta[((size_t)(bi*64+d2))*SEQL + l0 + lane] = sp;
  }
  const int which = ty >> 2, gq = ty & 3;
  float* dst = which ? Cm : Bm;
  size_t base = ((size_t)bi*SEQL + l0 + lane)*32 + gq*8;
  const int s0 = 2 + which*32 + gq*8;
  float4 f0, f1;
  f0.x = xd[lane][s0+0]; f0.y = xd[lane][s0+1]; f0.z = xd[lane][s0+2]; f0.w = xd[lane][s0+3];
  f1.x = xd[lane][s0+4]; f1.y = xd[lane][s0+5]; f1.z = xd[lane][s0+6]; f1.w = xd[lane][s0+7];
  *(float4*)(dst + base)     = f0;
  *(float4*)(dst + base + 4) = f1;
}

// ---------------- selective scan: 3-kernel chunked scan, chunk=64 ----------
__global__ __launch_bounds__(256) void scan_p1(const float* __restrict__ dlt,
    const float* __restrict__ xssm, const float* __restrict__ Bm,
    const float* __restrict__ A_log, float* __restrict__ cA, float* __restrict__ cH)
{
  const int tid = threadIdx.x;
  const int n = tid & 31;
  const int chunk = (blockIdx.x & 7)*8 + (tid >> 5);
  const int bd = blockIdx.x >> 3;
  const int b = bd >> 6, d = bd & 63;
  const int l0 = chunk << 6;
  const float Av2 = -expf(A_log[d*32+n]) * L2E;
  const float* del = dlt  + (size_t)bd*SEQL + l0;
  const float* xp  = xssm + (size_t)bd*SEQL + l0;
  const float* Bp  = Bm + ((size_t)b*SEQL + l0)*32 + n;
  float h = 0.0f, aP = 1.0f;
  #pragma unroll 4
  for (int i0=0;i0<64;i0+=4){
    float4 d4 = *(const float4*)(del+i0);
    float4 x4 = *(const float4*)(xp +i0);
    float b0 = Bp[(i0+0)*32], b1 = Bp[(i0+1)*32], b2 = Bp[(i0+2)*32], b3 = Bp[(i0+3)*32];
    float a0 = FAST_EXP2(d4.x*Av2); h = fmaf(a0,h, d4.x*b0*x4.x); aP *= a0;
    float a1 = FAST_EXP2(d4.y*Av2); h = fmaf(a1,h, d4.y*b1*x4.y); aP *= a1;
    float a2 = FAST_EXP2(d4.z*Av2); h = fmaf(a2,h, d4.z*b2*x4.z); aP *= a2;
    float a3 = FAST_EXP2(d4.w*Av2); h = fmaf(a3,h, d4.w*b3*x4.w); aP *= a3;
  }
  int idx = (bd*64+chunk)*32 + n;
  cA[idx] = aP; cH[idx] = h;
}

__global__ __launch_bounds__(128) void scan_comb(const float* __restrict__ cA,
    float* __restrict__ cH)
{
  const int gid = blockIdx.x*128 + threadIdx.x;   // 8192 = 256 bd x 32 n
  const int n = gid & 31, bd = gid >> 5;
  const size_t base = (size_t)bd*64*32 + n;
  float hrun = 0.0f;
  #pragma unroll 8
  for (int c=0;c<64;++c){
    float ac = cA[base + c*32];
    float hc = cH[base + c*32];
    cH[base + c*32] = hrun;                        // exclusive prefix
    hrun = fmaf(ac, hrun, hc);
  }
}

__global__ __launch_bounds__(256) void scan_p2(const float* __restrict__ dlt,
    const float* __restrict__ xssm, const float* __restrict__ Bm,
    const float* __restrict__ Cm, const float* __restrict__ A_log,
    const float* __restrict__ Dp, const float* __restrict__ sz,
    const float* __restrict__ cH, float* __restrict__ yt)
{
  const int tid = threadIdx.x;
  const int n = tid & 31;
  const int chunk = (blockIdx.x & 7)*8 + (tid >> 5);
  const int bd = blockIdx.x >> 3;
  const int b = bd >> 6, d = bd & 63;
  const int l0 = chunk << 6;
  const float Av2 = -expf(A_log[d*32+n]) * L2E;
  const float Dv = Dp[d];
  const float* del = dlt  + (size_t)bd*SEQL + l0;
  const float* xp  = xssm + (size_t)bd*SEQL + l0;
  const float* szp = sz   + (size_t)bd*SEQL + l0;
  const float* Bp  = Bm + ((size_t)b*SEQL + l0)*32 + n;
  const float* Cp  = Cm + ((size_t)b*SEQL + l0)*32 + n;
  float* yp = yt + (size_t)bd*SEQL + l0;
  float h = cH[(bd*64+chunk)*32 + n];
  #pragma unroll 2
  for (int i0=0;i0<64;i0+=4){
    float4 d4 = *(const float4*)(del+i0);
    float4 x4 = *(const float4*)(xp +i0);
    float4 s4 = *(const float4*)(szp+i0);
    float b0 = Bp[(i0+0)*32], b1 = Bp[(i0+1)*32], b2 = Bp[(i0+2)*32], b3 = Bp[(i0+3)*32];
    float c0 = Cp[(i0+0)*32], c1 = Cp[(i0+1)*32], c2 = Cp[(i0+2)*32], c3 = Cp[(i0+3)*32];
    float a0 = FAST_EXP2(d4.x*Av2); h = fmaf(a0,h, d4.x*b0*x4.x);
    float v0 = h*c0;
    float a1 = FAST_EXP2(d4.y*Av2); h = fmaf(a1,h, d4.y*b1*x4.y);
    float v1 = h*c1;
    float a2 = FAST_EXP2(d4.z*Av2); h = fmaf(a2,h, d4.z*b2*x4.z);
    float v2 = h*c2;
    float a3 = FAST_EXP2(d4.w*Av2); h = fmaf(a3,h, d4.w*b3*x4.w);
    float v3 = h*c3;
    v0 += __shfl_xor(v0,16); v0 += __shfl_xor(v0,8); v0 += __shfl_xor(v0,4);
    v0 += __shfl_xor(v0,2);  v0 += __shfl_xor(v0,1);
    v1 += __shfl_xor(v1,16); v1 += __shfl_xor(v1,8); v1 += __shfl_xor(v1,4);
    v1 += __shfl_xor(v1,2);  v1 += __shfl_xor(v1,1);
    v2 += __shfl_xor(v2,16); v2 += __shfl_xor(v2,8); v2 += __shfl_xor(v2,4);
    v2 += __shfl_xor(v2,2);  v2 += __shfl_xor(v2,1);
    v3 += __shfl_xor(v3,16); v3 += __shfl_xor(v3,8); v3 += __shfl_xor(v3,4);
    v3 += __shfl_xor(v3,2);  v3 += __shfl_xor(v3,1);
    if (n==0){
      yp[i0+0] = fmaf(x4.x, Dv, v0) * s4.x;
      yp[i0+1] = fmaf(x4.y, Dv, v1) * s4.y;
      yp[i0+2] = fmaf(x4.z, Dv, v2) * s4.z;
      yp[i0+3] = fmaf(x4.w, Dv, v3) * s4.w;
    }
  }
}

// ---------------- out_proj (64->32) into (b,c,l) = NCHW image --------------
__global__ __launch_bounds__(512) void outproj_k(const float* __restrict__ yt,
    const float* __restrict__ Wout, float* __restrict__ ym)
{
  __shared__ float ys[64][68];    // ys[l][d]
  const int tid = threadIdx.x, lane = tid & 63, ty = tid >> 6;
  const int bi = blockIdx.x >> 6;
  const int l0 = (blockIdx.x & 63) << 6;
  for (int r=ty; r<64; r+=8)
    ys[lane][r] = yt[((size_t)(bi*64+r))*SEQL + l0 + lane];
  __syncthreads();
  float yv[64];
  #pragma unroll
  for (int c=0;c<64;c+=4){
    float4 f = *(const float4*)(&ys[lane][c]);
    yv[c]=f.x; yv[c+1]=f.y; yv[c+2]=f.z; yv[c+3]=f.w;
  }
  #pragma unroll
  for (int jj=0;jj<4;++jj){
    int j = ty*4 + jj;
    const float* wr = Wout + j*64;
    float acc = 0.0f;
    #pragma unroll
    for (int c=0;c<64;++c) acc = fmaf(yv[c], wr[c], acc);
    ym[((size_t)(bi*32+j))*SEQL + l0 + lane] = acc;
  }
}

extern "C" void kernel_launch(void* const* d_in, const int* in_sizes, int n_in,
                              void* d_out, int out_size, void* d_ws, size_t ws_size,
                              hipStream_t stream) {
  const float* x        = (const float*)d_in[0];
  const float* conv1_w  = (const float*)d_in[1];
  const float* conv1_b  = (const float*)d_in[2];
  const float* conv2_w  = (const float*)d_in[3];
  const float* conv2_b  = (const float*)d_in[4];
  const float* ln_g     = (const float*)d_in[5];
  const float* ln_b     = (const float*)d_in[6];
  const float* in_proj_w= (const float*)d_in[7];
  const float* conv1d_w = (const float*)d_in[8];
  const float* conv1d_b = (const float*)d_in[9];
  const float* x_proj_w = (const float*)d_in[10];
  const float* dt_proj_w= (const float*)d_in[11];
  const float* dt_proj_b= (const float*)d_in[12];
  const float* A_log    = (const float*)d_in[13];
  const float* Dp       = (const float*)d_in[14];
  const float* out_proj_w=(const float*)d_in[15];
  const float* smooth_w = (const float*)d_in[16];
  const float* smooth_b = (const float*)d_in[17];
  float* out = (float*)d_out;

  float* ws = (float*)d_ws;
  float* t      = ws;                 // (4,64,64,64)  1048576  (free after conv2)
  float* x2     = t      + 1048576;   // (4,32,4096)    524288
  float* xm_pre = x2     + 524288;    // (4,64,4096)   1048576
  float* xm2    = xm_pre + 1048576;   // (4,64,4096)   1048576
  float* szb    = xm2    + 1048576;   // (4,64,4096)   1048576
  float* dlt    = szb    + 1048576;   // (4,64,4096)   1048576
  float* Bmat   = dlt    + 1048576;   // (4,4096,32)    524288
  float* Cmat   = Bmat   + 524288;    // (4,4096,32)    524288
  float* yt     = Cmat   + 524288;    // (4,64,4096)   1048576
  float* ym     = yt     + 1048576;   // (4,32,4096)    524288
  float* cA     = t;                  // (256,64,32)    524288 (aliases t)
  float* cH     = t + 524288;         // (256,64,32)    524288 (aliases t)

  dim3 cblk(64,4);
  conv3x3_k<32,64,8,true ,false><<<dim3(16,8,4), cblk, 0, stream>>>(x,  conv1_w, conv1_b, nullptr, t);
  conv3x3_k<64,32,4,false,true ><<<dim3(16,8,4), cblk, 0, stream>>>(t,  conv2_w, conv2_b, x,       x2);
  ln_inproj_k <<<256, 512, 0, stream>>>(x2, ln_g, ln_b, in_proj_w, xm_pre, szb);
  xproj_k     <<<256, 512, 0, stream>>>(xm_pre, conv1d_w, conv1d_b, x_proj_w, dt_proj_w, dt_proj_b,
                                        xm2, dlt, Bmat, Cmat);
  scan_p1     <<<2048, 256, 0, stream>>>(dlt, xm2, Bmat, A_log, cA, cH);
  scan_comb   <<<64,   128, 0, stream>>>(cA, cH);
  scan_p2     <<<2048, 256, 0, stream>>>(dlt, xm2, Bmat, Cmat, A_log, Dp, szb, cH, yt);
  outproj_k   <<<256, 512, 0, stream>>>(yt, out_proj_w, ym);
  conv3x3_k<32,32,4,false,false><<<dim3(16,8,4), cblk, 0, stream>>>(ym, smooth_w, smooth_b, nullptr, out);
}

// Round 4
// 302.389 us; speedup vs baseline: 1.7141x; 1.0475x over previous
//
#include <hip/hip_runtime.h>
#include <math.h>

#define SEQL 4096
#define L2E 1.44269504088896340736f

#if defined(__has_builtin)
#if __has_builtin(__builtin_amdgcn_exp2f)
#define FAST_EXP2(x) __builtin_amdgcn_exp2f(x)
#endif
#endif
#ifndef FAST_EXP2
#define FAST_EXP2(x) exp2f(x)
#endif

__device__ __forceinline__ float sigmoid_f(float x){ return 1.0f/(1.0f+expf(-x)); }

// ---------------- conv 3x3, pad 1, 64x64 image, LDS-staged ----------------
// block: 256 thr = 4 waves. lane=w, ty=h-offset (4 rows per block).
// Each thread: 1 output row x COG output channels. Halo cols staged in LDS
// (no shuffles). CIT input channels staged per barrier pair.
template<int CI, int CO, int COG, int CIT, bool RELU, bool RES>
__global__ __launch_bounds__(256) void conv3x3_k(const float* __restrict__ in,
    const float* __restrict__ wgt, const float* __restrict__ bias,
    const float* __restrict__ res, float* __restrict__ out)
{
  __shared__ float tile[CIT][6][66];            // [ci_local][row][1+w], halo cols 0,65
  const int lane = threadIdx.x & 63;            // w
  const int ty   = threadIdx.x >> 6;            // 0..3
  const int h0   = blockIdx.x * 4;
  const int h    = h0 + ty;
  const int co0  = blockIdx.y * COG;
  const int b    = blockIdx.z;
  float acc[COG];
  #pragma unroll
  for (int u=0;u<COG;++u) acc[u] = bias[co0+u];

  for (int cig = 0; cig < CI; cig += CIT){
    __syncthreads();
    // stage CIT channels x 6 rows (h0-1 .. h0+4) x 66 cols
    const int NR = CIT*6;
    for (int r = ty; r < NR; r += 4){
      int cl = r / 6, rr = r - cl*6;
      int hh = h0 - 1 + rr;
      const float* p = in + ((size_t)(b*CI + cig + cl))*4096 + hh*64 + lane;
      float v = (hh>=0 && hh<64) ? *p : 0.0f;
      tile[cl][rr][1+lane] = v;
      if (lane==0)  tile[cl][rr][0]  = 0.0f;
      if (lane==63) tile[cl][rr][65] = 0.0f;
    }
    __syncthreads();
    #pragma unroll 2
    for (int cl=0; cl<CIT; ++cl){
      float iv[3][3];
      #pragma unroll
      for (int r=0;r<3;++r)
        #pragma unroll
        for (int c=0;c<3;++c)
          iv[r][c] = tile[cl][ty+r][lane+c];    // input[h-1+r][w-1+c]
      #pragma unroll
      for (int u=0;u<COG;++u){
        const float* wp = wgt + ((size_t)(co0+u)*CI + cig + cl)*9;  // uniform -> s_load
        #pragma unroll
        for (int r=0;r<3;++r)
          #pragma unroll
          for (int c=0;c<3;++c)
            acc[u] = fmaf(iv[r][c], wp[r*3+c], acc[u]);
      }
    }
  }
  #pragma unroll
  for (int u=0;u<COG;++u){
    size_t ob = ((size_t)(b*CO+co0+u))*4096 + (size_t)h*64 + lane;
    float v = acc[u];
    if constexpr (RES)  v += res[ob];
    if constexpr (RELU) v = fmaxf(v, 0.0f);
    out[ob] = v;
  }
}

// ---------------- LayerNorm(32) + in_proj (32->128) + silu on z half --------
__global__ __launch_bounds__(512) void ln_inproj_k(const float* __restrict__ x2,
    const float* __restrict__ g, const float* __restrict__ be,
    const float* __restrict__ Wip, float* __restrict__ xm_pre, float* __restrict__ sz)
{
  __shared__ float xn[64][36];
  const int tid = threadIdx.x, lane = tid & 63, ty = tid >> 6;
  const int bi = blockIdx.x >> 6;
  const int l0 = (blockIdx.x & 63) << 6;
  if (ty == 0){
    const float* row = x2 + (size_t)bi*131072 + (size_t)(l0+lane)*32;
    float v[32];
    #pragma unroll
    for (int c=0;c<32;c+=4){
      float4 f = *(const float4*)(row + c);
      v[c]=f.x; v[c+1]=f.y; v[c+2]=f.z; v[c+3]=f.w;
    }
    float p[8];
    #pragma unroll
    for (int j2=0;j2<8;++j2) p[j2]=v[j2];
    #pragma unroll
    for (int i=8;i<32;i+=8){
      #pragma unroll
      for (int j2=0;j2<8;++j2) p[j2]+=v[i+j2];
    }
    float mu = (((p[0]+p[1])+(p[2]+p[3]))+((p[4]+p[5])+(p[6]+p[7]))) * 0.03125f;
    float q[8];
    #pragma unroll
    for (int j2=0;j2<8;++j2){ float dd=v[j2]-mu; q[j2]=dd*dd; }
    #pragma unroll
    for (int i=8;i<32;i+=8){
      #pragma unroll
      for (int j2=0;j2<8;++j2){ float dd=v[i+j2]-mu; q[j2]+=dd*dd; }
    }
    float var = (((q[0]+q[1])+(q[2]+q[3]))+((q[4]+q[5])+(q[6]+q[7]))) * 0.03125f;
    float rstd = 1.0f / sqrtf(var + 1e-5f);
    #pragma unroll
    for (int c=0;c<32;++c) xn[lane][c] = (v[c]-mu)*rstd*g[c] + be[c];
  }
  __syncthreads();
  float xv[32];
  #pragma unroll
  for (int c=0;c<32;c+=4){
    float4 f = *(const float4*)(&xn[lane][c]);
    xv[c]=f.x; xv[c+1]=f.y; xv[c+2]=f.z; xv[c+3]=f.w;
  }
  #pragma unroll
  for (int jj=0;jj<16;++jj){
    int j = (ty<<4) + jj;
    const float* wr = Wip + j*32;
    float acc = 0.0f;
    #pragma unroll
    for (int c=0;c<32;++c) acc = fmaf(xv[c], wr[c], acc);
    size_t o = ((size_t)(bi*64 + (j & 63)))*SEQL + l0 + lane;
    if (j < 64) xm_pre[o] = acc;
    else        sz[o] = acc * sigmoid_f(acc);
  }
}

// ---- fused: depthwise causal conv1d+silu, x_proj (64->66), dt_proj+softplus, B/C split
__global__ __launch_bounds__(512) void xproj_k(const float* __restrict__ xm_pre,
    const float* __restrict__ cw, const float* __restrict__ cb,
    const float* __restrict__ Wxp, const float* __restrict__ Wdt,
    const float* __restrict__ bdt, float* __restrict__ xm2,
    float* __restrict__ delta, float* __restrict__ Bm, float* __restrict__ Cm)
{
  __shared__ float xs[64][68];   // xs[d][c] = xm_pre[l0-3+c], c in 0..66
  __shared__ float xt[64][68];   // xt[l][d] = silu(conv) transposed
  __shared__ float xd[64][68];   // xd[l][j], j in 0..65
  const int tid = threadIdx.x, lane = tid & 63, ty = tid >> 6;
  const int bi = blockIdx.x >> 6;
  const int l0 = (blockIdx.x & 63) << 6;
  for (int r=ty; r<64; r+=8){
    const float* src = xm_pre + ((size_t)(bi*64+r))*SEQL + l0;
    float v = 0.0f;
    if (l0 + lane - 3 >= 0) v = src[lane-3];
    xs[r][lane] = v;
    if (lane < 3) xs[r][64+lane] = src[61+lane];
  }
  __syncthreads();
  for (int r=ty; r<64; r+=8){
    float w0=cw[r*4], w1=cw[r*4+1], w2=cw[r*4+2], w3=cw[r*4+3], bv=cb[r];
    float a = xs[r][lane]*w0 + xs[r][lane+1]*w1 + xs[r][lane+2]*w2 + xs[r][lane+3]*w3 + bv;
    float s = a * sigmoid_f(a);
    xt[lane][r] = s;
    xm2[((size_t)(bi*64+r))*SEQL + l0 + lane] = s;
  }
  __syncthreads();
  float xv[64];
  #pragma unroll
  for (int c=0;c<64;c+=4){
    float4 f = *(const float4*)(&xt[lane][c]);
    xv[c]=f.x; xv[c+1]=f.y; xv[c+2]=f.z; xv[c+3]=f.w;
  }
  for (int j=ty; j<66; j+=8){
    const float* wr = Wxp + j*64;
    float acc = 0.0f;
    #pragma unroll
    for (int c=0;c<64;++c) acc = fmaf(xv[c], wr[c], acc);
    xd[lane][j] = acc;
  }
  __syncthreads();
  float dt0 = xd[lane][0], dt1 = xd[lane][1];
  #pragma unroll
  for (int k=0;k<8;++k){
    int d2 = ty*8 + k;
    float v = dt0*Wdt[d2*2] + dt1*Wdt[d2*2+1] + bdt[d2];
    float sp = fmaxf(v,0.0f) + log1pf(expf(-fabsf(v)));
    delta[((size_t)(bi*64+d2))*SEQL + l0 + lane] = sp;
  }
  const int which = ty >> 2, gq = ty & 3;
  float* dst = which ? Cm : Bm;
  size_t base = ((size_t)bi*SEQL + l0 + lane)*32 + gq*8;
  const int s0 = 2 + which*32 + gq*8;
  float4 f0, f1;
  f0.x = xd[lane][s0+0]; f0.y = xd[lane][s0+1]; f0.z = xd[lane][s0+2]; f0.w = xd[lane][s0+3];
  f1.x = xd[lane][s0+4]; f1.y = xd[lane][s0+5]; f1.z = xd[lane][s0+6]; f1.w = xd[lane][s0+7];
  *(float4*)(dst + base)     = f0;
  *(float4*)(dst + base + 4) = f1;
}

// ---------------- selective scan: 3-kernel chunked scan, chunk=64 ----------
__global__ __launch_bounds__(256) void scan_p1(const float* __restrict__ dlt,
    const float* __restrict__ xssm, const float* __restrict__ Bm,
    const float* __restrict__ A_log, float* __restrict__ cA, float* __restrict__ cH)
{
  const int tid = threadIdx.x;
  const int n = tid & 31;
  const int chunk = (blockIdx.x & 7)*8 + (tid >> 5);
  const int bd = blockIdx.x >> 3;
  const int b = bd >> 6, d = bd & 63;
  const int l0 = chunk << 6;
  const float Av2 = -expf(A_log[d*32+n]) * L2E;
  const float* del = dlt  + (size_t)bd*SEQL + l0;
  const float* xp  = xssm + (size_t)bd*SEQL + l0;
  const float* Bp  = Bm + ((size_t)b*SEQL + l0)*32 + n;
  float h = 0.0f, aP = 1.0f;
  #pragma unroll 4
  for (int i0=0;i0<64;i0+=4){
    float4 d4 = *(const float4*)(del+i0);
    float4 x4 = *(const float4*)(xp +i0);
    float b0 = Bp[(i0+0)*32], b1 = Bp[(i0+1)*32], b2 = Bp[(i0+2)*32], b3 = Bp[(i0+3)*32];
    float a0 = FAST_EXP2(d4.x*Av2); h = fmaf(a0,h, d4.x*b0*x4.x); aP *= a0;
    float a1 = FAST_EXP2(d4.y*Av2); h = fmaf(a1,h, d4.y*b1*x4.y); aP *= a1;
    float a2 = FAST_EXP2(d4.z*Av2); h = fmaf(a2,h, d4.z*b2*x4.z); aP *= a2;
    float a3 = FAST_EXP2(d4.w*Av2); h = fmaf(a3,h, d4.w*b3*x4.w); aP *= a3;
  }
  int idx = (bd*64+chunk)*32 + n;
  cA[idx] = aP; cH[idx] = h;
}

__global__ __launch_bounds__(128) void scan_comb(const float* __restrict__ cA,
    float* __restrict__ cH)
{
  const int gid = blockIdx.x*128 + threadIdx.x;   // 8192 = 256 bd x 32 n
  const int n = gid & 31, bd = gid >> 5;
  const size_t base = (size_t)bd*64*32 + n;
  float hrun = 0.0f;
  #pragma unroll 8
  for (int c=0;c<64;++c){
    float ac = cA[base + c*32];
    float hc = cH[base + c*32];
    cH[base + c*32] = hrun;                        // exclusive prefix
    hrun = fmaf(ac, hrun, hc);
  }
}

__global__ __launch_bounds__(256) void scan_p2(const float* __restrict__ dlt,
    const float* __restrict__ xssm, const float* __restrict__ Bm,
    const float* __restrict__ Cm, const float* __restrict__ A_log,
    const float* __restrict__ Dp, const float* __restrict__ sz,
    const float* __restrict__ cH, float* __restrict__ yt)
{
  const int tid = threadIdx.x;
  const int n = tid & 31;
  const int chunk = (blockIdx.x & 7)*8 + (tid >> 5);
  const int bd = blockIdx.x >> 3;
  const int b = bd >> 6, d = bd & 63;
  const int l0 = chunk << 6;
  const float Av2 = -expf(A_log[d*32+n]) * L2E;
  const float Dv = Dp[d];
  const float* del = dlt  + (size_t)bd*SEQL + l0;
  const float* xp  = xssm + (size_t)bd*SEQL + l0;
  const float* szp = sz   + (size_t)bd*SEQL + l0;
  const float* Bp  = Bm + ((size_t)b*SEQL + l0)*32 + n;
  const float* Cp  = Cm + ((size_t)b*SEQL + l0)*32 + n;
  float* yp = yt + (size_t)bd*SEQL + l0;
  float h = cH[(bd*64+chunk)*32 + n];
  #pragma unroll 2
  for (int i0=0;i0<64;i0+=4){
    float4 d4 = *(const float4*)(del+i0);
    float4 x4 = *(const float4*)(xp +i0);
    float4 s4 = *(const float4*)(szp+i0);
    float b0 = Bp[(i0+0)*32], b1 = Bp[(i0+1)*32], b2 = Bp[(i0+2)*32], b3 = Bp[(i0+3)*32];
    float c0 = Cp[(i0+0)*32], c1 = Cp[(i0+1)*32], c2 = Cp[(i0+2)*32], c3 = Cp[(i0+3)*32];
    float a0 = FAST_EXP2(d4.x*Av2); h = fmaf(a0,h, d4.x*b0*x4.x);
    float v0 = h*c0;
    float a1 = FAST_EXP2(d4.y*Av2); h = fmaf(a1,h, d4.y*b1*x4.y);
    float v1 = h*c1;
    float a2 = FAST_EXP2(d4.z*Av2); h = fmaf(a2,h, d4.z*b2*x4.z);
    float v2 = h*c2;
    float a3 = FAST_EXP2(d4.w*Av2); h = fmaf(a3,h, d4.w*b3*x4.w);
    float v3 = h*c3;
    v0 += __shfl_xor(v0,16); v0 += __shfl_xor(v0,8); v0 += __shfl_xor(v0,4);
    v0 += __shfl_xor(v0,2);  v0 += __shfl_xor(v0,1);
    v1 += __shfl_xor(v1,16); v1 += __shfl_xor(v1,8); v1 += __shfl_xor(v1,4);
    v1 += __shfl_xor(v1,2);  v1 += __shfl_xor(v1,1);
    v2 += __shfl_xor(v2,16); v2 += __shfl_xor(v2,8); v2 += __shfl_xor(v2,4);
    v2 += __shfl_xor(v2,2);  v2 += __shfl_xor(v2,1);
    v3 += __shfl_xor(v3,16); v3 += __shfl_xor(v3,8); v3 += __shfl_xor(v3,4);
    v3 += __shfl_xor(v3,2);  v3 += __shfl_xor(v3,1);
    if (n==0){
      yp[i0+0] = fmaf(x4.x, Dv, v0) * s4.x;
      yp[i0+1] = fmaf(x4.y, Dv, v1) * s4.y;
      yp[i0+2] = fmaf(x4.z, Dv, v2) * s4.z;
      yp[i0+3] = fmaf(x4.w, Dv, v3) * s4.w;
    }
  }
}

// ---------------- out_proj (64->32) into (b,c,l) = NCHW image --------------
__global__ __launch_bounds__(512) void outproj_k(const float* __restrict__ yt,
    const float* __restrict__ Wout, float* __restrict__ ym)
{
  __shared__ float ys[64][68];    // ys[l][d]
  const int tid = threadIdx.x, lane = tid & 63, ty = tid >> 6;
  const int bi = blockIdx.x >> 6;
  const int l0 = (blockIdx.x & 63) << 6;
  for (int r=ty; r<64; r+=8)
    ys[lane][r] = yt[((size_t)(bi*64+r))*SEQL + l0 + lane];
  __syncthreads();
  float yv[64];
  #pragma unroll
  for (int c=0;c<64;c+=4){
    float4 f = *(const float4*)(&ys[lane][c]);
    yv[c]=f.x; yv[c+1]=f.y; yv[c+2]=f.z; yv[c+3]=f.w;
  }
  #pragma unroll
  for (int jj=0;jj<4;++jj){
    int j = ty*4 + jj;
    const float* wr = Wout + j*64;
    float acc = 0.0f;
    #pragma unroll
    for (int c=0;c<64;++c) acc = fmaf(yv[c], wr[c], acc);
    ym[((size_t)(bi*32+j))*SEQL + l0 + lane] = acc;
  }
}

extern "C" void kernel_launch(void* const* d_in, const int* in_sizes, int n_in,
                              void* d_out, int out_size, void* d_ws, size_t ws_size,
                              hipStream_t stream) {
  const float* x        = (const float*)d_in[0];
  const float* conv1_w  = (const float*)d_in[1];
  const float* conv1_b  = (const float*)d_in[2];
  const float* conv2_w  = (const float*)d_in[3];
  const float* conv2_b  = (const float*)d_in[4];
  const float* ln_g     = (const float*)d_in[5];
  const float* ln_b     = (const float*)d_in[6];
  const float* in_proj_w= (const float*)d_in[7];
  const float* conv1d_w = (const float*)d_in[8];
  const float* conv1d_b = (const float*)d_in[9];
  const float* x_proj_w = (const float*)d_in[10];
  const float* dt_proj_w= (const float*)d_in[11];
  const float* dt_proj_b= (const float*)d_in[12];
  const float* A_log    = (const float*)d_in[13];
  const float* Dp       = (const float*)d_in[14];
  const float* out_proj_w=(const float*)d_in[15];
  const float* smooth_w = (const float*)d_in[16];
  const float* smooth_b = (const float*)d_in[17];
  float* out = (float*)d_out;

  float* ws = (float*)d_ws;
  float* t      = ws;                 // (4,64,64,64)  1048576  (free after conv2)
  float* x2     = t      + 1048576;   // (4,32,4096)    524288
  float* xm_pre = x2     + 524288;    // (4,64,4096)   1048576
  float* xm2    = xm_pre + 1048576;   // (4,64,4096)   1048576
  float* szb    = xm2    + 1048576;   // (4,64,4096)   1048576
  float* dlt    = szb    + 1048576;   // (4,64,4096)   1048576
  float* Bmat   = dlt    + 1048576;   // (4,4096,32)    524288
  float* Cmat   = Bmat   + 524288;    // (4,4096,32)    524288
  float* yt     = Cmat   + 524288;    // (4,64,4096)   1048576
  float* ym     = yt     + 1048576;   // (4,32,4096)    524288
  float* cA     = t;                  // (256,64,32)    524288 (aliases t)
  float* cH     = t + 524288;         // (256,64,32)    524288 (aliases t)

  // conv1: 32->64, COG=8 -> grid (16,8,4)=512 blocks
  conv3x3_k<32,64,8,8,true ,false><<<dim3(16,8,4), 256, 0, stream>>>(x,  conv1_w, conv1_b, nullptr, t);
  // conv2: 64->32 + residual, COG=4 -> grid (16,8,4)=512 blocks
  conv3x3_k<64,32,4,8,false,true ><<<dim3(16,8,4), 256, 0, stream>>>(t,  conv2_w, conv2_b, x,       x2);
  ln_inproj_k <<<256, 512, 0, stream>>>(x2, ln_g, ln_b, in_proj_w, xm_pre, szb);
  xproj_k     <<<256, 512, 0, stream>>>(xm_pre, conv1d_w, conv1d_b, x_proj_w, dt_proj_w, dt_proj_b,
                                        xm2, dlt, Bmat, Cmat);
  scan_p1     <<<2048, 256, 0, stream>>>(dlt, xm2, Bmat, A_log, cA, cH);
  scan_comb   <<<64,   128, 0, stream>>>(cA, cH);
  scan_p2     <<<2048, 256, 0, stream>>>(dlt, xm2, Bmat, Cmat, A_log, Dp, szb, cH, yt);
  outproj_k   <<<256, 512, 0, stream>>>(yt, out_proj_w, ym);
  // smooth: 32->32, COG=4 -> grid (16,8,4)=512 blocks
  conv3x3_k<32,32,4,8,false,false><<<dim3(16,8,4), 256, 0, stream>>>(ym, smooth_w, smooth_b, nullptr, out);
}